// Round 8
// baseline (404.079 us; speedup 1.0000x reference)
//
#include <hip/hip_runtime.h>

#define OUT_S 7
#define NPTS  49                  // 7x7 sample points
#define C_CH  256
#define ELEMS (C_CH * NPTS)       // 12544 floats per roi
#define ITERS (ELEMS / 256)       // 49 iterations per 256-thread block
#define NXCD  8

__global__ __launch_bounds__(256, 8) void roi_align_fused(
    const float* __restrict__ p2, const float* __restrict__ p3,
    const float* __restrict__ p4, const float* __restrict__ p5,
    const float* __restrict__ prop, const int* __restrict__ Hp,
    const int* __restrict__ Wp, float* __restrict__ out, int K_per_img)
{
    __shared__ int4   s_off[NPTS];   // o00,o01,o10,o11 per sample point
    __shared__ float2 s_w[NPTS];     // wx, wy per sample point

    // XCD-aware bijective swizzle: HW sends block bid to XCD bid%8; remap so
    // each XCD owns a CONTIGUOUS roi range (same image -> same fm planes in
    // its private L2, capturing cross-roi reuse). Bijective when N%8==0.
    const int nwg = gridDim.x;
    int n = blockIdx.x;
    if ((nwg & (NXCD - 1)) == 0) {
        const int q = nwg >> 3;              // rois per XCD
        n = (n & (NXCD - 1)) * q + (n >> 3);
    }

    const int t = threadIdx.x;       // 0..255
    const int b = n / K_per_img;     // batch image

    const float W = (float)Wp[0];
    const float H = (float)Hp[0];

    const float4 box = reinterpret_cast<const float4*>(prop)[n];
    const float x1 = box.x, y1 = box.y, x2 = box.z, y2 = box.w;

    // level selection — reference op order:
    // lev = clip(floor(4 + log2(sqrt(max(dx*dy,1e-6))/224)), 2, 5)
    const float area = fmaxf((x2 - x1) * (y2 - y1), 1e-6f);
    const float sqa  = sqrtf(area);
    int lev = (int)floorf(4.0f + log2f(sqa / 224.0f));
    lev = min(max(lev, 2), 5);

    const float* fm; int Hf, Wf;
    if      (lev == 2) { fm = p2; Hf = 200; Wf = 200; }
    else if (lev == 3) { fm = p3; Hf = 100; Wf = 100; }
    else if (lev == 4) { fm = p4; Hf = 50;  Wf = 50;  }
    else               { fm = p5; Hf = 25;  Wf = 25;  }
    const int plane = Hf * Wf;       // <= 40000, 32-bit offsets

    // ---- precompute the 49 sample-point geometries into LDS (SoA) ----
    if (t < NPTS) {
        const int iy = t / OUT_S;
        const int ix = t - iy * OUT_S;

        // grid_sample coords, align_corners=True, border pad (reference order)
        const float x1n = x1 / W * 2.0f - 1.0f;
        const float x2n = x2 / W * 2.0f - 1.0f;
        const float y1n = y1 / H * 2.0f - 1.0f;
        const float y2n = y2 / H * 2.0f - 1.0f;
        const float tx = (float)ix * (1.0f / 6.0f);  // linspace(0,1,7)[ix]
        const float ty = (float)iy * (1.0f / 6.0f);
        const float gx = x1n + (x2n - x1n) * tx;
        const float gy = y1n + (y2n - y1n) * ty;

        float x = (gx + 1.0f) * 0.5f * (float)(Wf - 1);
        float y = (gy + 1.0f) * 0.5f * (float)(Hf - 1);
        x = fminf(fmaxf(x, 0.0f), (float)(Wf - 1));
        y = fminf(fmaxf(y, 0.0f), (float)(Hf - 1));

        const float x0f = floorf(x), y0f = floorf(y);
        const float wx = x - x0f,  wy = y - y0f;
        const int xi0 = (int)x0f,  yi0 = (int)y0f;
        const int xi1 = min(xi0 + 1, Wf - 1);
        const int yi1 = min(yi0 + 1, Hf - 1);

        s_off[t] = make_int4(yi0 * Wf + xi0, yi0 * Wf + xi1,
                             yi1 * Wf + xi0, yi1 * Wf + xi1);
        s_w[t]   = make_float2(wx, wy);
    }
    __syncthreads();

    const float* basep = fm + (size_t)b * C_CH * (size_t)plane;
    float*       outp  = out + (size_t)n * ELEMS;

    // every lane active: idx = t + 256*j covers all (c,p) of this roi;
    // stores are contiguous 1024 B per block-iteration (full 64B lines)
    #pragma unroll 4
    for (int j = 0; j < ITERS; ++j) {
        const int idx = t + 256 * j;
        const int c   = (unsigned)idx / NPTS;       // magic-mul div by 49
        const int p   = idx - c * NPTS;

        const int4   o = s_off[p];
        const float2 w = s_w[p];

        const float* pb = basep + (size_t)c * plane;
        const float v00 = pb[o.x];
        const float v01 = pb[o.y];
        const float v10 = pb[o.z];
        const float v11 = pb[o.w];

        // reference's exact two-stage lerp
        const float omwx = 1.0f - w.x, omwy = 1.0f - w.y;
        const float top = v00 * omwx + v01 * w.x;
        const float bot = v10 * omwx + v11 * w.x;
        const float r   = top * omwy + bot * w.y;

        __builtin_nontemporal_store(r, &outp[idx]);
    }
}

extern "C" void kernel_launch(void* const* d_in, const int* in_sizes, int n_in,
                              void* d_out, int out_size, void* d_ws, size_t ws_size,
                              hipStream_t stream) {
    const float* p2   = (const float*)d_in[0];
    const float* p3   = (const float*)d_in[1];
    const float* p4   = (const float*)d_in[2];
    const float* p5   = (const float*)d_in[3];
    const float* prop = (const float*)d_in[4];
    const int*   Hp   = (const int*)d_in[5];
    const int*   Wp   = (const int*)d_in[6];
    float* out = (float*)d_out;

    const int N = in_sizes[4] / 4;                    // B*K rois
    const int B = in_sizes[0] / (C_CH * 200 * 200);   // p2 = [B,256,200,200]
    const int K = N / (B > 0 ? B : 1);                // proposals per image

    roi_align_fused<<<N, 256, 0, stream>>>(p2, p3, p4, p5, prop, Hp, Wp, out, K);
}

// Round 9
// 393.005 us; speedup vs baseline: 1.0282x; 1.0282x over previous
//
#include <hip/hip_runtime.h>

#define OUT_S 7
#define NPTS  49                  // 7x7 sample points
#define C_CH  256
#define ELEMS (C_CH * NPTS)       // 12544 floats per roi
#define ITERS (ELEMS / 256)       // 49 iterations per 256-thread block
#define NXCD  8
#define MAXB  64                  // max (image,level) buckets supported

// ---- shared level-selection math (must be bit-identical in both kernels) ----
__device__ __forceinline__ int roi_level(float x1, float y1, float x2, float y2) {
    const float area = fmaxf((x2 - x1) * (y2 - y1), 1e-6f);
    const float sqa  = sqrtf(area);
    int lev = (int)floorf(4.0f + log2f(sqa / 224.0f));
    return min(max(lev, 2), 5);
}

// Pre-pass: counting-sort roi indices by (image, level) into order[0..N).
// Same-bucket rois become adjacent -> same-plane, same-trip-count blocks get
// co-scheduled on an XCD, making channel sweeps phase-coherent so the 4 MiB
// per-XCD L2 (and 32 KiB per-CU L1) capture cross-roi line reuse.
__global__ void build_order(const float* __restrict__ prop, int N, int K,
                            int* __restrict__ order)
{
    __shared__ int s_cnt[MAXB];
    __shared__ int s_off[MAXB];
    const int t = threadIdx.x;               // 256 threads, single workgroup
    if (t < MAXB) s_cnt[t] = 0;
    __syncthreads();

    int myb[16];                             // supports N <= 4096
    const int per = (N + 255) / 256;
    for (int i = 0; i < per; ++i) {
        const int n = t + 256 * i;
        if (n < N) {
            const float4 bx = reinterpret_cast<const float4*>(prop)[n];
            const int lev = roi_level(bx.x, bx.y, bx.z, bx.w);
            const int b   = (n / K) * 4 + (lev - 2);
            myb[i] = b;
            atomicAdd(&s_cnt[b], 1);
        }
    }
    __syncthreads();
    if (t == 0) {                            // exclusive scan over <=64 buckets
        int acc = 0;
        for (int j = 0; j < MAXB; ++j) { s_off[j] = acc; acc += s_cnt[j]; }
    }
    __syncthreads();
    for (int i = 0; i < per; ++i) {
        const int n = t + 256 * i;
        if (n < N) {
            const int pos = atomicAdd(&s_off[myb[i]], 1);
            order[pos] = n;
        }
    }
}

__global__ __launch_bounds__(256, 8) void roi_align_fused(
    const float* __restrict__ p2, const float* __restrict__ p3,
    const float* __restrict__ p4, const float* __restrict__ p5,
    const float* __restrict__ prop, const int* __restrict__ Hp,
    const int* __restrict__ Wp, float* __restrict__ out, int K_per_img,
    const int* __restrict__ order)
{
    __shared__ int4   s_offs[NPTS];  // o00,o01,o10,o11 per sample point
    __shared__ float2 s_w[NPTS];     // wx, wy per sample point

    // XCD-affine pickup from the sorted list: blocks with bid%8==x run on
    // XCD x and take the contiguous sorted range [x*N/8, (x+1)*N/8) ->
    // each XCD sees same-(image,level) rois back-to-back.
    const int nwg = gridDim.x;
    int m = blockIdx.x;
    if ((nwg & (NXCD - 1)) == 0)
        m = (m & (NXCD - 1)) * (nwg >> 3) + (m >> 3);
    const int n = order ? order[m] : m;

    const int t = threadIdx.x;       // 0..255
    const int b = n / K_per_img;     // batch image

    const float W = (float)Wp[0];
    const float H = (float)Hp[0];

    const float4 box = reinterpret_cast<const float4*>(prop)[n];
    const float x1 = box.x, y1 = box.y, x2 = box.z, y2 = box.w;

    const int lev = roi_level(x1, y1, x2, y2);

    const float* fm; int Hf, Wf;
    if      (lev == 2) { fm = p2; Hf = 200; Wf = 200; }
    else if (lev == 3) { fm = p3; Hf = 100; Wf = 100; }
    else if (lev == 4) { fm = p4; Hf = 50;  Wf = 50;  }
    else               { fm = p5; Hf = 25;  Wf = 25;  }
    const int plane = Hf * Wf;       // <= 40000, 32-bit offsets

    // ---- precompute the 49 sample-point geometries into LDS (SoA) ----
    if (t < NPTS) {
        const int iy = t / OUT_S;
        const int ix = t - iy * OUT_S;

        // grid_sample coords, align_corners=True, border pad (reference order)
        const float x1n = x1 / W * 2.0f - 1.0f;
        const float x2n = x2 / W * 2.0f - 1.0f;
        const float y1n = y1 / H * 2.0f - 1.0f;
        const float y2n = y2 / H * 2.0f - 1.0f;
        const float tx = (float)ix * (1.0f / 6.0f);  // linspace(0,1,7)[ix]
        const float ty = (float)iy * (1.0f / 6.0f);
        const float gx = x1n + (x2n - x1n) * tx;
        const float gy = y1n + (y2n - y1n) * ty;

        float x = (gx + 1.0f) * 0.5f * (float)(Wf - 1);
        float y = (gy + 1.0f) * 0.5f * (float)(Hf - 1);
        x = fminf(fmaxf(x, 0.0f), (float)(Wf - 1));
        y = fminf(fmaxf(y, 0.0f), (float)(Hf - 1));

        const float x0f = floorf(x), y0f = floorf(y);
        const float wx = x - x0f,  wy = y - y0f;
        const int xi0 = (int)x0f,  yi0 = (int)y0f;
        const int xi1 = min(xi0 + 1, Wf - 1);
        const int yi1 = min(yi0 + 1, Hf - 1);

        s_offs[t] = make_int4(yi0 * Wf + xi0, yi0 * Wf + xi1,
                              yi1 * Wf + xi0, yi1 * Wf + xi1);
        s_w[t]    = make_float2(wx, wy);
    }
    __syncthreads();

    const float* basep = fm + (size_t)b * C_CH * (size_t)plane;
    float*       outp  = out + (size_t)n * ELEMS;

    // every lane active: idx = t + 256*j covers all (c,p) of this roi;
    // stores are contiguous 1024 B per block-iteration (full 64B lines)
    #pragma unroll 4
    for (int j = 0; j < ITERS; ++j) {
        const int idx = t + 256 * j;
        const int c   = (unsigned)idx / NPTS;       // magic-mul div by 49
        const int p   = idx - c * NPTS;

        const int4   o = s_offs[p];
        const float2 w = s_w[p];

        const float* pb = basep + (size_t)c * plane;
        const float v00 = pb[o.x];
        const float v01 = pb[o.y];
        const float v10 = pb[o.z];
        const float v11 = pb[o.w];

        // reference's exact two-stage lerp
        const float omwx = 1.0f - w.x, omwy = 1.0f - w.y;
        const float top = v00 * omwx + v01 * w.x;
        const float bot = v10 * omwx + v11 * w.x;
        const float r   = top * omwy + bot * w.y;

        __builtin_nontemporal_store(r, &outp[idx]);
    }
}

extern "C" void kernel_launch(void* const* d_in, const int* in_sizes, int n_in,
                              void* d_out, int out_size, void* d_ws, size_t ws_size,
                              hipStream_t stream) {
    const float* p2   = (const float*)d_in[0];
    const float* p3   = (const float*)d_in[1];
    const float* p4   = (const float*)d_in[2];
    const float* p5   = (const float*)d_in[3];
    const float* prop = (const float*)d_in[4];
    const int*   Hp   = (const int*)d_in[5];
    const int*   Wp   = (const int*)d_in[6];
    float* out = (float*)d_out;

    const int N = in_sizes[4] / 4;                    // B*K rois
    const int B = in_sizes[0] / (C_CH * 200 * 200);   // p2 = [B,256,200,200]
    const int K = N / (B > 0 ? B : 1);                // proposals per image

    int* order = nullptr;
    if (ws_size >= (size_t)N * sizeof(int) && N <= 4096 && B * 4 <= MAXB) {
        order = (int*)d_ws;
        build_order<<<1, 256, 0, stream>>>(prop, N, K, order);
    }
    roi_align_fused<<<N, 256, 0, stream>>>(p2, p3, p4, p5, prop, Hp, Wp, out,
                                           K, order);
}